// Round 1
// baseline (44.452 us; speedup 1.0000x reference)
//
#include <hip/hip_runtime.h>

// out = l*X + g*rowsum(X) + b,  X: [4096, 8192] fp32
// One block per row. Each thread holds 8 float4 (32 floats) in registers so
// X is fetched from HBM exactly once; rowsum via wave shfl + LDS combine.

constexpr int ROWS = 4096;
constexpr int COLS = 8192;
constexpr int BLOCK = 256;
constexpr int VEC_PER_ROW = COLS / 4;          // 2048 float4
constexpr int PER_THREAD = VEC_PER_ROW / BLOCK; // 8

__global__ __launch_bounds__(BLOCK) void equinn_kernel(
    const float* __restrict__ X,
    const float* __restrict__ lp,
    const float* __restrict__ gp,
    const float* __restrict__ bp,
    float* __restrict__ out)
{
    const int row = blockIdx.x;
    const int tid = threadIdx.x;

    const float4* __restrict__ Xr =
        reinterpret_cast<const float4*>(X + (size_t)row * COLS);
    float4* __restrict__ Or =
        reinterpret_cast<float4*>(out + (size_t)row * COLS);

    // Load the whole row into registers (coalesced: lane i reads float4 i,
    // stride BLOCK between iterations), accumulating a per-thread sum.
    float4 v[PER_THREAD];
    float s = 0.f;
#pragma unroll
    for (int i = 0; i < PER_THREAD; ++i) {
        v[i] = Xr[tid + i * BLOCK];
        s += (v[i].x + v[i].y) + (v[i].z + v[i].w);
    }

    // Wave-64 butterfly reduction.
#pragma unroll
    for (int off = 32; off > 0; off >>= 1)
        s += __shfl_xor(s, off, 64);

    // Combine the 4 waves through LDS.
    __shared__ float wsum[BLOCK / 64];
    const int lane = tid & 63;
    const int wid  = tid >> 6;
    if (lane == 0) wsum[wid] = s;
    __syncthreads();
    const float rowsum = (wsum[0] + wsum[1]) + (wsum[2] + wsum[3]);

    const float l = lp[0];
    const float g = gp[0];
    const float b = bp[0];
    const float add = g * rowsum + b;

#pragma unroll
    for (int i = 0; i < PER_THREAD; ++i) {
        float4 o;
        o.x = __builtin_fmaf(l, v[i].x, add);
        o.y = __builtin_fmaf(l, v[i].y, add);
        o.z = __builtin_fmaf(l, v[i].z, add);
        o.w = __builtin_fmaf(l, v[i].w, add);
        Or[tid + i * BLOCK] = o;
    }
}

extern "C" void kernel_launch(void* const* d_in, const int* in_sizes, int n_in,
                              void* d_out, int out_size, void* d_ws, size_t ws_size,
                              hipStream_t stream)
{
    const float* X = (const float*)d_in[0];
    const float* l = (const float*)d_in[1];
    const float* g = (const float*)d_in[2];
    const float* b = (const float*)d_in[3];
    float* out = (float*)d_out;

    equinn_kernel<<<ROWS, BLOCK, 0, stream>>>(X, l, g, b, out);
}